// Round 14
// baseline (234.138 us; speedup 1.0000x reference)
//
#include <hip/hip_runtime.h>
#include <math.h>

#define NN 2048
#define BATCH 8
#define FDIM 128
#define NWORDS (BATCH * NN * 64)   // one 32-bit word per 32 adj elements

// ---------------- kernel 0: adj (float 0/1) -> connectivity bitmask --------
// Pure streaming: 1 word per thread, 8 float4 loads (own 128B line), 1 store.
// Bit j of word g  <->  adj[g*32 + j] > 0 ; diagonal forced here.
__global__ __launch_bounds__(256) void k_conv(const float* __restrict__ adj,
                                              unsigned* __restrict__ mask) {
    const int g = blockIdx.x * 256 + threadIdx.x;      // word id 0..NWORDS-1
    const float4* src = (const float4*)(adj + (size_t)g * 32);
    unsigned w = 0u;
#pragma unroll
    for (int i = 0; i < 8; i++) {
        float4 v = src[i];
        w |= (v.x > 0.f ? 1u : 0u) << (i * 4 + 0);
        w |= (v.y > 0.f ? 1u : 0u) << (i * 4 + 1);
        w |= (v.z > 0.f ? 1u : 0u) << (i * 4 + 2);
        w |= (v.w > 0.f ? 1u : 0u) << (i * 4 + 3);
    }
    const int n = (g >> 6) & (NN - 1);     // row within batch (64 words/row)
    const int wordIdx = g & 63;
    if (wordIdx == (n >> 5)) w |= 1u << (n & 31);      // forced diagonal
    mask[g] = w;
}

// ---------------- kernel 2: Wh = (h+pe) @ W ; s1 = Wh@a1 ; s2 = Wh@a2 ------
// pe computed inline (fused k_pe): sin/cos per element during tile load.
__global__ __launch_bounds__(512) void k_wh(const float* __restrict__ h,
                                            const float* __restrict__ W,
                                            const float* __restrict__ a,
                                            float* __restrict__ Wh,
                                            float* __restrict__ s1,
                                            float* __restrict__ s2) {
    __shared__ float w_lds[64 * 128];     // 32 KB: W[kp*64 + k][c]
    __shared__ float hpe_lds[64 * 68];    // 17.4 KB: rows 64, stride 68 (bank pad)
    const int b  = blockIdx.y;
    const int n0 = blockIdx.x * 64;
    const int t  = threadIdx.x;
    const int tc = t & 15;                // col group -> cols tc*8..+7
    const int tr = t >> 4;                // row group 0..31 -> rows tr*2..+1
    const float C2 = -0.07195578415606394f;   // -ln(1e4)/128

    float acc[2][8];
#pragma unroll
    for (int i = 0; i < 2; i++)
#pragma unroll
        for (int j = 0; j < 8; j++) acc[i][j] = 0.f;

    for (int kp = 0; kp < 2; ++kp) {
        {   // load W half: 2048 float4 by 512 threads
            const float4* wsrc = (const float4*)(W + kp * 64 * 128);
            float4* wdst = (float4*)w_lds;
#pragma unroll
            for (int q = 0; q < 4; q++) wdst[t + q * 512] = wsrc[t + q * 512];
        }
        {   // load h tile + inline positional encoding
#pragma unroll
            for (int q = 0; q < 2; q++) {
                int f = t + q * 512;          // float4 index 0..1023
                int r = f >> 4;               // row 0..63
                int k4 = (f & 15) << 2;       // k offset 0..60
                int n = n0 + r;
                int kk = kp * 64 + k4;
                float4 hv = *(const float4*)(h + ((size_t)b * NN + n) * FDIM + kk);
                float fn = (float)n;
                float decay = 1.f + expf(-fn * 0.01f);
                float dt0 = expf((float)kk * C2);        // pair (kk,kk+1)
                float dt1 = expf((float)(kk + 2) * C2);  // pair (kk+2,kk+3)
                float ang0 = fn * dt0, ang1 = fn * dt1;
                hv.x += sinf(ang0) * decay;
                hv.y += cosf(ang0) * decay;
                hv.z += sinf(ang1) * decay;
                hv.w += cosf(ang1) * decay;
                *(float4*)(hpe_lds + r * 68 + k4) = hv;
            }
        }
        __syncthreads();
#pragma unroll 4
        for (int k = 0; k < 64; k++) {
            float wv[8];
            float4 wa = *(float4*)(w_lds + k * 128 + tc * 8);
            float4 wb = *(float4*)(w_lds + k * 128 + tc * 8 + 4);
            wv[0] = wa.x; wv[1] = wa.y; wv[2] = wa.z; wv[3] = wa.w;
            wv[4] = wb.x; wv[5] = wb.y; wv[6] = wb.z; wv[7] = wb.w;
#pragma unroll
            for (int i = 0; i < 2; i++) {
                float hv = hpe_lds[(tr * 2 + i) * 68 + k];
#pragma unroll
                for (int j = 0; j < 8; j++) acc[i][j] = fmaf(hv, wv[j], acc[i][j]);
            }
        }
        __syncthreads();
    }

    float a1v[8], a2v[8];
#pragma unroll
    for (int j = 0; j < 8; j++) { a1v[j] = a[tc * 8 + j]; a2v[j] = a[FDIM + tc * 8 + j]; }
#pragma unroll
    for (int i = 0; i < 2; i++) {
        int n = n0 + tr * 2 + i;
        float* dst = Wh + ((size_t)b * NN + n) * FDIM + tc * 8;
        *(float4*)dst = make_float4(acc[i][0], acc[i][1], acc[i][2], acc[i][3]);
        *(float4*)(dst + 4) = make_float4(acc[i][4], acc[i][5], acc[i][6], acc[i][7]);
        float p1 = 0.f, p2 = 0.f;
#pragma unroll
        for (int j = 0; j < 8; j++) {
            p1 = fmaf(acc[i][j], a1v[j], p1);
            p2 = fmaf(acc[i][j], a2v[j], p2);
        }
#pragma unroll
        for (int off = 1; off < 16; off <<= 1) {   // reduce across the 16 tc lanes
            p1 += __shfl_xor(p1, off, 64);
            p2 += __shfl_xor(p2, off, 64);
        }
        if (tc == 0) {
            s1[(size_t)b * NN + n] = p1;
            s2[(size_t)b * NN + n] = p2;
        }
    }
}

// ---------------- kernel 3: mask-fed row softmax, column-sum partials ------
// grid (128 chunks of 16 rows, 8 b), 256 threads = 4 waves, 4 rows/wave.
// Per row: 8 broadcast mask dwords (L2) instead of 8KB of adj floats.
// s2 and c_acc in REGISTERS; exp recomputed in pass 2 (VGPR ~90, no spill).
__global__ __launch_bounds__(256, 4) void k_attn(const unsigned* __restrict__ mask,
                                                 const float* __restrict__ s1,
                                                 const float* __restrict__ s2,
                                                 float* __restrict__ c_part) {
    const int b = blockIdx.y;
    const int chunk = blockIdx.x;      // 16 rows per chunk
    const int t = threadIdx.x;
    const int wave = t >> 6;
    const int lane = t & 63;
    __shared__ float slice[4][NN];     // 32 KB, per-wave private

    const float* s2b = s2 + (size_t)b * NN;
    float s2v[32];
#pragma unroll
    for (int kq = 0; kq < 8; kq++) {
        float4 v = ((const float4*)s2b)[kq * 64 + lane];
        s2v[kq * 4 + 0] = v.x; s2v[kq * 4 + 1] = v.y;
        s2v[kq * 4 + 2] = v.z; s2v[kq * 4 + 3] = v.w;
    }
    float c_acc[32];
#pragma unroll
    for (int j = 0; j < 32; j++) c_acc[j] = 0.f;

    const int nbase = chunk * 16 + wave * 4;
    const float* s1b = s1 + (size_t)b * NN;
    const unsigned sh = (lane & 7) << 2;         // bit base within mask word

#pragma unroll 1
    for (int ri = 0; ri < 4; ri++) {
        const int n = nbase + ri;
        const unsigned* mrow = mask + ((size_t)b * NN + n) * 64;
        const float s1n = s1b[n];
        unsigned mw[8];
#pragma unroll
        for (int kq = 0; kq < 8; kq++) mw[kq] = mrow[kq * 8 + (lane >> 3)];
        float z = 0.f;
#pragma unroll
        for (int kq = 0; kq < 8; kq++)
#pragma unroll
            for (int e = 0; e < 4; e++) {
                float x = s1n + s2v[kq * 4 + e];
                float ev = fmaxf(x, 0.2f * x);               // LeakyReLU
                z += ((mw[kq] >> (sh + e)) & 1u) ? __expf(ev) : 0.f;
            }
#pragma unroll
        for (int off = 32; off; off >>= 1) z += __shfl_xor(z, off, 64);
        const float rz = (n != 0) ? 1.f / z : 0.f;   // valid[:,0]=False
#pragma unroll
        for (int kq = 0; kq < 8; kq++)
#pragma unroll
            for (int e = 0; e < 4; e++) {
                float x = s1n + s2v[kq * 4 + e];
                float ev = fmaxf(x, 0.2f * x);
                float p = ((mw[kq] >> (sh + e)) & 1u) ? __expf(ev) : 0.f;
                c_acc[kq * 4 + e] = fmaf(p, rz, c_acc[kq * 4 + e]);
            }
    }

    // write own slice (pure store, no init needed), then cross-wave combine
#pragma unroll
    for (int kq = 0; kq < 8; kq++)
        *(float4*)&slice[wave][kq * 256 + lane * 4] =
            make_float4(c_acc[kq * 4 + 0], c_acc[kq * 4 + 1],
                        c_acc[kq * 4 + 2], c_acc[kq * 4 + 3]);
    __syncthreads();

    float* dst = c_part + ((size_t)b * 128 + chunk) * NN;
#pragma unroll
    for (int q = 0; q < 2; q++) {
        int idx = t + q * 256;   // float4 index 0..511
        float4 v0 = ((const float4*)slice[0])[idx];
        float4 v1 = ((const float4*)slice[1])[idx];
        float4 v2 = ((const float4*)slice[2])[idx];
        float4 v3 = ((const float4*)slice[3])[idx];
        ((float4*)dst)[idx] = make_float4(v0.x + v1.x + v2.x + v3.x,
                                          v0.y + v1.y + v2.y + v3.y,
                                          v0.z + v1.z + v2.z + v3.z,
                                          v0.w + v1.w + v2.w + v3.w);
    }
}

// ---------------- kernel 4: reduce c_part + g_part = c^T * Wh partials -----
// grid (32 m-chunks of 64, 8 b), 256 threads
__global__ __launch_bounds__(256) void k_gpre(const float* __restrict__ Wh,
                                              const float* __restrict__ c_part,
                                              float* __restrict__ g_part) {
    const int b = blockIdx.y;
    const int mc = blockIdx.x;
    const int m0 = mc * 64;
    const int t = threadIdx.x;
    __shared__ float red[256];
    __shared__ float c_lds[64];

    // phase 1: c[b][m0+mi] = sum over 128 chunk-partials (4 waves x 32 each)
    {
        const int mi = t & 63;
        const int w = t >> 6;
        const float* cp = c_part + (size_t)b * 128 * NN + m0 + mi;
        float s = 0.f;
#pragma unroll 8
        for (int j = 0; j < 32; j++) s += cp[(size_t)(w * 32 + j) * NN];
        red[w * 64 + mi] = s;
    }
    __syncthreads();
    if (t < 64) c_lds[t] = red[t] + red[t + 64] + red[t + 128] + red[t + 192];
    __syncthreads();

    // phase 2: partial g over this m-chunk
    const int o = t & 127;
    const int mh = t >> 7;              // 0/1
    float acc = 0.f;
    const float* whb = Wh + ((size_t)b * NN + m0 + mh * 32) * FDIM;
#pragma unroll 4
    for (int mm = 0; mm < 32; mm++)
        acc = fmaf(c_lds[mh * 32 + mm], whb[mm * FDIM + o], acc);
    g_part[((size_t)(mc * 2 + mh)) * (BATCH * FDIM) + b * FDIM + o] = acc;
}

// ---------------- kernel 5: out = elu( (sum of 64 partials) / 2047 ) -------
__global__ void k_elu(const float* __restrict__ g_part, float* __restrict__ out) {
    int i = blockIdx.x * 256 + threadIdx.x;    // 0..1023 = b*128+o
    if (i < BATCH * FDIM) {
        float s = 0.f;
#pragma unroll 8
        for (int p = 0; p < 64; p++) s += g_part[p * (BATCH * FDIM) + i];
        float g = s * (1.0f / 2047.0f);
        out[i] = g > 0.f ? g : expm1f(g);
    }
}

extern "C" void kernel_launch(void* const* d_in, const int* in_sizes, int n_in,
                              void* d_out, int out_size, void* d_ws, size_t ws_size,
                              hipStream_t stream) {
    (void)in_sizes; (void)n_in; (void)out_size; (void)ws_size;
    const float* h   = (const float*)d_in[0];
    const float* adj = (const float*)d_in[1];
    const float* W   = (const float*)d_in[2];
    const float* a   = (const float*)d_in[3];
    float* out = (float*)d_out;

    char* ws = (char*)d_ws;
    float* Wh       = (float*)ws;                                 // 8*2048*128
    float* s1       = Wh + (size_t)BATCH * NN * FDIM;             // 8*2048
    float* s2       = s1 + (size_t)BATCH * NN;                    // 8*2048
    float* c_part   = s2 + (size_t)BATCH * NN;                    // 8*128*2048
    float* g_part   = c_part + (size_t)BATCH * 128 * NN;          // 64*8*128
    unsigned* mask  = (unsigned*)(g_part + 64 * BATCH * FDIM);    // 8*2048*64

    hipLaunchKernelGGL(k_conv, dim3(NWORDS / 256), dim3(256), 0, stream,
                       adj, mask);
    hipLaunchKernelGGL(k_wh, dim3(NN / 64, BATCH), dim3(512), 0, stream,
                       h, W, a, Wh, s1, s2);
    hipLaunchKernelGGL(k_attn, dim3(NN / 16, BATCH), dim3(256), 0, stream,
                       mask, s1, s2, c_part);
    hipLaunchKernelGGL(k_gpre, dim3(NN / 64, BATCH), dim3(256), 0, stream,
                       Wh, c_part, g_part);
    hipLaunchKernelGGL(k_elu, dim3(4), dim3(256), 0, stream, g_part, out);
}